// Round 12
// baseline (129.662 us; speedup 1.0000x reference)
//
#include <hip/hip_runtime.h>
#include <hip/hip_bf16.h>

// Problem constants
#define BATCH 64
#define NATOM 120
#define NNB 10
#define NBOND 250
#define AFDIM 82
#define BFDIM 6
#define HREAL 300
#define HP 320            // padded H (bf16 activation row stride); pad cols hold exact 0
#define NCT32 10          // 10 col-tiles of 32 -> 320
#define MA (BATCH*NATOM)  // 7680
#define MB (BATCH*NBOND)  // 16000

typedef short short8 __attribute__((ext_vector_type(8)));   // 8 bf16 (4 VGPRs)
typedef float f32x16 __attribute__((ext_vector_type(16)));  // 32x32 MFMA accumulator
typedef unsigned int u32;
typedef u32 u32x2 __attribute__((ext_vector_type(2)));
typedef unsigned short u16;
typedef unsigned char u8;

__device__ __forceinline__ float bflo(u32 v) { return __builtin_bit_cast(float, v << 16); }
__device__ __forceinline__ float bfhi(u32 v) { return __builtin_bit_cast(float, v & 0xffff0000u); }
__device__ __forceinline__ float bfu(u16 v) { return __builtin_bit_cast(float, (u32)v << 16); }
__device__ __forceinline__ u16 f2bf(float f) {
    __hip_bfloat16 h = __float2bfloat16(f);
    return __builtin_bit_cast(u16, h);
}
__device__ __forceinline__ int imin(int a, int b) { return a < b ? a : b; }

// ================= front dispatch: fc1 (self-packed W) + 5 weight packs + pk16, ONE launch =================
// block ranges: [0,300) fc1 4-wave tiles | [300,550) pack jobs | [550,850) pk16
struct PackJob { const float* W; short8* dst; int Kreal, KT, KTfull, ktOff, blk0; };
struct Front {
    const float *A1, *W_fc1;
    __hip_bfloat16* af0;
    const int *mn, *agp, *bgp; u16* pk16;        // pk16[i] = mask<<15 | ag<<8 | bg
    PackJob j[5];
};

#define FC1_TILES  300    // (60 bx) x (5 by)
#define PACK_BASE2 300    // 5 jobs x 50 blocks
#define PK_BASE2   550
#define FRONT_BLKS 850
#define FRONT_LDS  (2 * 6 * 64 * 16)   // 12288 B (fc1 W panel)

__global__ __launch_bounds__(256) void k_front(Front cfg) {
    extern __shared__ short8 Wl[];
    const int bid = blockIdx.x;
    const int tid = threadIdx.x;
    if (bid < FC1_TILES) {
        // ---- fc1: af0 = relu(A1 @ W_fc1); W panel self-packed from fp32 (same math as old prep) ----
        const int bx   = bid % 60;
        const int ct0  = (bid / 60) * 2;
        const int lane = tid & 63;
        const int wv   = tid >> 6;
#pragma unroll
        for (int i = 0; i < 3; ++i) {            // 768 panel entries / 256 threads
            const int id = i * 256 + tid;
            const int l2 = id & 63;
            const int kt = (id >> 6) % 6;
            const int c  = id / (6 * 64);
            const int col = (ct0 + c) * 32 + (l2 & 31);
            const int kbase = kt * 16 + (l2 >> 5) * 8;
            short8 v;
#pragma unroll
            for (int jj = 0; jj < 8; ++jj) {
                const int k = kbase + jj;
                const float f = (k < AFDIM && col < HREAL) ? cfg.W_fc1[(size_t)k * HREAL + col] : 0.f;
                v[jj] = (short)f2bf(f);
            }
            Wl[(c * 6 + kt) * 64 + l2] = v;
        }
        __syncthreads();

        const int m0   = bx * 128 + wv * 32;
        const int r1   = m0 + (lane & 31);
        const int koff = (lane >> 5) * 8;
        const float* src = cfg.A1 + (size_t)r1 * AFDIM;
        short8 a[6];
#pragma unroll
        for (int g = 0; g < 6; ++g) {
#pragma unroll
            for (int jj = 0; jj < 8; ++jj) {
                const int k = g * 16 + koff + jj;
                const float f = (k < AFDIM) ? src[k] : 0.f;
                a[g][jj] = (short)f2bf(f);
            }
        }
        f32x16 acc[2];
#pragma unroll
        for (int r = 0; r < 16; ++r) { acc[0][r] = 0.f; acc[1][r] = 0.f; }
        const short8* w0 = Wl + lane;
        const short8* w1 = Wl + 6 * 64 + lane;
#pragma unroll
        for (int g = 0; g < 6; ++g) {
            acc[0] = __builtin_amdgcn_mfma_f32_32x32x16_bf16(a[g], w0[g * 64], acc[0], 0, 0, 0);
            acc[1] = __builtin_amdgcn_mfma_f32_32x32x16_bf16(a[g], w1[g * 64], acc[1], 0, 0, 0);
        }
#pragma unroll
        for (int c = 0; c < 2; ++c) {
            const int col = (ct0 + c) * 32 + (lane & 31);
#pragma unroll
            for (int r = 0; r < 16; ++r) {
                const int row = m0 + (r & 3) + 8 * (r >> 2) + 4 * (lane >> 5);
                cfg.af0[(size_t)row * HP + col] = __float2bfloat16(fmaxf(acc[c][r], 0.f));
            }
        }
    } else if (bid < PK_BASE2) {
        // ---- weight packs (consumed only by later dispatches) ----
        int ji = 0;
#pragma unroll
        for (int i = 1; i < 5; ++i) if (bid >= cfg.j[i].blk0) ji = i;
        const PackJob J = cfg.j[ji];
        int id = (bid - J.blk0) * 256 + tid;
        int n = NCT32 * J.KT * 64;
        if (id >= n) return;
        int lane = id & 63;
        int kt = (id >> 6) % J.KT;
        int ct = id / (J.KT * 64);
        int col = ct * 32 + (lane & 31);
        int kbase = kt * 16 + (lane >> 5) * 8;
        short8 v;
#pragma unroll
        for (int jj = 0; jj < 8; ++jj) {
            int k = kbase + jj;
            float f = (k < J.Kreal && col < HREAL) ? J.W[(size_t)k * HREAL + col] : 0.f;
            v[jj] = (short)f2bf(f);
        }
        J.dst[(size_t)(ct * J.KTfull + J.ktOff + kt) * 64 + lane] = v;
    } else {
        int id = (bid - PK_BASE2) * 256 + tid;    // exact multiple (76800)
        u16 w = 0;
        if (cfg.mn[id])
            w = (u16)(0x8000u | ((u32)cfg.agp[id] << 8) | (u32)cfg.bgp[id]);
        cfg.pk16[id] = w;
    }
}

// ================= bot GEMM (R7-proven): afn = relu([af|nei]@W_ga + b_ga), 2 ct, 80KB panel =================
#define BOT_LDS (2 * 40 * 64 * 16)     // 81920 B -> 2 blocks/CU, 300 blocks = 1 round
__global__ __launch_bounds__(256)
void k_gemm_bot(const __hip_bfloat16* __restrict__ af,
                const __hip_bfloat16* __restrict__ neib,
                const short8* __restrict__ W,
                const float* __restrict__ b_ga,
                __hip_bfloat16* __restrict__ afn) {
    extern __shared__ short8 Wl[];             // [2*40*64]
    const int tid  = threadIdx.x;
    const int lane = tid & 63;
    const int wv   = tid >> 6;
    const int m0   = blockIdx.x * 128 + wv * 32;
    const int ct0  = blockIdx.y * 2;
    const int r1   = m0 + (lane & 31);
    const int koff = (lane >> 5) * 8;

    {
        const short8* wsrc = W + (size_t)ct0 * 40 * 64;
#pragma unroll
        for (int i = 0; i < 20; ++i) Wl[i * 256 + tid] = wsrc[i * 256 + tid];
    }
    __syncthreads();

    f32x16 acc[2];
#pragma unroll
    for (int r = 0; r < 16; ++r) { acc[0][r] = 0.f; acc[1][r] = 0.f; }
    const short8* w0 = Wl + lane;
    const short8* w1 = Wl + 40 * 64 + lane;

#pragma unroll
    for (int ch = 0; ch < 4; ++ch) {
        short8 a[10];
#pragma unroll
        for (int kt = 0; kt < 10; ++kt) {
            const int g = ch * 10 + kt;
            if (g < 20)
                a[kt] = *reinterpret_cast<const short8*>(af + (size_t)r1 * HP + g * 16 + koff);
            else
                a[kt] = *reinterpret_cast<const short8*>(neib + (size_t)r1 * HP + (g - 20) * 16 + koff);
        }
#pragma unroll
        for (int kt = 0; kt < 10; ++kt) {
            const int g = ch * 10 + kt;
            acc[0] = __builtin_amdgcn_mfma_f32_32x32x16_bf16(a[kt], w0[g * 64], acc[0], 0, 0, 0);
            acc[1] = __builtin_amdgcn_mfma_f32_32x32x16_bf16(a[kt], w1[g * 64], acc[1], 0, 0, 0);
        }
    }

#pragma unroll
    for (int c = 0; c < 2; ++c) {
        const int col = (ct0 + c) * 32 + (lane & 31);
        const float bb = (col < HREAL) ? b_ga[col] : 0.f;
#pragma unroll
        for (int r = 0; r < 16; ++r) {
            const int row = m0 + (r & 3) + 8 * (r >> 2) + 4 * (lane >> 5);
            afn[(size_t)row * HP + col] = __float2bfloat16(fmaxf(acc[c][r] + bb, 0.f));
        }
    }
}

// ================= fused nu-GEMM + gather (R11-proven); 50,944 B LDS -> 3 blocks/CU, 1 round =================
#define NUG_LDS (20480 + 7680 + 16000 + 2400 + 4000 + 384)   // 50944
__global__ __launch_bounds__(256)
void k_nu_gather(const __hip_bfloat16* __restrict__ af,
                 const short8* __restrict__ pWnei,
                 const float* __restrict__ bond,      // [B][250][6] fp32
                 const float* __restrict__ Wgn_bond,  // W_gc_nei + 300*300, [6][300]
                 const float* __restrict__ b_gn,      // [300]
                 const u16* __restrict__ pk16,
                 u32* __restrict__ nei) {             // [MA][160]
    extern __shared__ char smraw[];
    short8* WL  = (short8*)smraw;                  // [20*64]
    u16*    TL  = (u16*)(smraw + 20480);           // [120][32]
    u32*    BL  = (u32*)(smraw + 28160);           // [250][16] bondgc slice
    u16*    PLh = (u16*)(smraw + 44160);           // [1200]
    u16*    BFL = (u16*)(smraw + 46560);           // [250][8] bond bf16
    u16*    WS  = (u16*)(smraw + 50560);           // [6][32]  W bond-part slice bf16
    const int b   = blockIdx.x;
    const int ct  = blockIdx.y;
    const int tid = threadIdx.x;

    // ---- stage ----
    {
        const short8* wsrc = pWnei + (size_t)ct * 20 * 64;
#pragma unroll
        for (int i = 0; i < 5; ++i) WL[i * 256 + tid] = wsrc[i * 256 + tid];
    }
    for (int i = tid; i < NBOND * 8; i += 256) {
        const int r = i >> 3, k = i & 7;
        const float f = (k < BFDIM) ? bond[(size_t)(b * NBOND + r) * BFDIM + k] : 0.f;
        BFL[i] = f2bf(f);
    }
    if (tid < 192) {
        const int k = tid >> 5, c = tid & 31;
        const int col = ct * 32 + c;
        const float f = (col < HREAL) ? Wgn_bond[(size_t)k * HREAL + col] : 0.f;
        WS[tid] = f2bf(f);
    }
    for (int i = tid; i < 600; i += 256)
        reinterpret_cast<u32*>(PLh)[i] = reinterpret_cast<const u32*>(pk16)[(size_t)b * 600 + i];
    __syncthreads();

    // ---- bondgc slice: BL[r][cp] = bf16pair( sum_k bond[r,k]*W[k,col] + bias ) ----
    for (int i = tid; i < NBOND * 16; i += 256) {
        const int r = i >> 4, cp = i & 15;
        const int col0 = ct * 32 + 2 * cp;
        float lo = 0.f, hi = 0.f;
#pragma unroll
        for (int k = 0; k < BFDIM; ++k) {
            const float bv = bfu(BFL[r * 8 + k]);
            const u32 wv2 = *reinterpret_cast<const u32*>(&WS[k * 32 + 2 * cp]);
            lo += bv * bflo(wv2);
            hi += bv * bfhi(wv2);
        }
        const float v0 = (col0     < HREAL) ? lo + b_gn[col0]     : 0.f;
        const float v1 = (col0 + 1 < HREAL) ? hi + b_gn[col0 + 1] : 0.f;
        BL[r * 16 + cp] = (u32)f2bf(v0) | ((u32)f2bf(v1) << 16);
    }

    // ---- GEMM: TL = af[b] @ W_nei[ct] ----
    {
        const int lane = tid & 63;
        const int wv   = tid >> 6;
        const int r1   = imin(wv * 32 + (lane & 31), NATOM - 1);
        const int koff = (lane >> 5) * 8;
        const __hip_bfloat16* arow = af + (size_t)(b * NATOM + r1) * HP + koff;
        f32x16 acc;
#pragma unroll
        for (int r = 0; r < 16; ++r) acc[r] = 0.f;
        const short8* w0 = WL + lane;
#pragma unroll
        for (int ch = 0; ch < 2; ++ch) {
            short8 a[10];
#pragma unroll
            for (int kt = 0; kt < 10; ++kt)
                a[kt] = *reinterpret_cast<const short8*>(arow + (ch * 10 + kt) * 16);
#pragma unroll
            for (int kt = 0; kt < 10; ++kt)
                acc = __builtin_amdgcn_mfma_f32_32x32x16_bf16(a[kt], w0[(ch * 10 + kt) * 64], acc, 0, 0, 0);
        }
        const int col = lane & 31;
#pragma unroll
        for (int r = 0; r < 16; ++r) {
            const int row = wv * 32 + (r & 3) + 8 * (r >> 2) + 4 * (lane >> 5);
            if (row < NATOM) TL[row * 32 + col] = f2bf(acc[r]);
        }
    }
    __syncthreads();

    // ---- gather: nei = sum_j relu(T[ag] + bondgc[bg]) ----
    for (int i = tid; i < NATOM * 16; i += 256) {
        const int row = i >> 4, cp = i & 15;
        float lo = 0.f, hi = 0.f;
#pragma unroll
        for (int j = 0; j < NNB; ++j) {
            const u16 w = PLh[row * NNB + j];
            if (w & 0x8000) {
                const int a  = (w >> 8) & 0x7f;
                const int bo = w & 0xff;
                const u32 ta = *reinterpret_cast<const u32*>(&TL[a * 32 + 2 * cp]);
                const u32 tb = BL[bo * 16 + cp];
                lo += fmaxf(bflo(ta) + bflo(tb), 0.f);
                hi += fmaxf(bfhi(ta) + bfhi(tb), 0.f);
            }
        }
        nei[(size_t)(b * NATOM + row) * (HP / 2) + ct * 16 + cp] =
            (u32)f2bf(lo) | ((u32)f2bf(hi) << 16);
    }
}

// ================= fused final (R11-proven); 51,064 B -> 3 blocks/CU, 1 round =================
#define FIN_LDS (20480 + 7680 + 16000 + 2400 + 120 + 4000 + 384)   // 51064
__global__ __launch_bounds__(256)
void k_final_fused(const __hip_bfloat16* __restrict__ af,
                   const short8* __restrict__ pWfd,    // fc2 ct 0..9 | fc2a ct 10..19
                   const float* __restrict__ bond,     // [B][250][6] fp32
                   const float* __restrict__ W_fc2b,   // [6][300] fp32
                   const u16* __restrict__ pk16,
                   const int* __restrict__ maska,
                   float* __restrict__ out) {          // [MA][300]
    extern __shared__ char smraw[];
    short8* WL  = (short8*)smraw;                      // [20*64]
    u16*    AL  = (u16*)(smraw + 20480);               // A2f [120][32]
    u32*    BL  = (u32*)(smraw + 28160);               // bnb [250][16]
    u16*    PLh = (u16*)(smraw + 44160);               // [1200]
    u8*     ML  = (u8*)(smraw + 46560);                // [120]
    u16*    BFL = (u16*)(smraw + 46680);               // [250][8]
    u16*    WS  = (u16*)(smraw + 50680);               // [6][32]
    float*  GL  = (float*)smraw;                       // [120][32] gathered sums (reuses WL)
    const int b   = blockIdx.x;
    const int ct  = blockIdx.y;
    const int tid = threadIdx.x;
    const int lane = tid & 63;
    const int wv   = tid >> 6;

    // ---- stage A ----
    {
        const short8* w2a = pWfd + (size_t)(NCT32 + ct) * 20 * 64;
#pragma unroll
        for (int i = 0; i < 5; ++i) WL[i * 256 + tid] = w2a[i * 256 + tid];
    }
    for (int i = tid; i < NBOND * 8; i += 256) {
        const int r = i >> 3, k = i & 7;
        const float f = (k < BFDIM) ? bond[(size_t)(b * NBOND + r) * BFDIM + k] : 0.f;
        BFL[i] = f2bf(f);
    }
    if (tid < 192) {
        const int k = tid >> 5, c = tid & 31;
        const int col = ct * 32 + c;
        const float f = (col < HREAL) ? W_fc2b[(size_t)k * HREAL + col] : 0.f;
        WS[tid] = f2bf(f);
    }
    for (int i = tid; i < 600; i += 256)
        reinterpret_cast<u32*>(PLh)[i] = reinterpret_cast<const u32*>(pk16)[(size_t)b * 600 + i];
    for (int i = tid; i < NATOM; i += 256) ML[i] = (u8)(maska[b * NATOM + i] != 0);
    __syncthreads();

    // ---- bnb slice ----
    for (int i = tid; i < NBOND * 16; i += 256) {
        const int r = i >> 4, cp = i & 15;
        float lo = 0.f, hi = 0.f;
#pragma unroll
        for (int k = 0; k < BFDIM; ++k) {
            const float bv = bfu(BFL[r * 8 + k]);
            const u32 wv2 = *reinterpret_cast<const u32*>(&WS[k * 32 + 2 * cp]);
            lo += bv * bflo(wv2);
            hi += bv * bfhi(wv2);
        }
        BL[r * 16 + cp] = (u32)f2bf(lo) | ((u32)f2bf(hi) << 16);
    }

    // ---- GEMM_a: AL = af @ W_fc2a[ct] ----
    const int r1   = imin(wv * 32 + (lane & 31), NATOM - 1);
    const int koff = (lane >> 5) * 8;
    const __hip_bfloat16* arow = af + (size_t)(b * NATOM + r1) * HP + koff;
    {
        f32x16 acc1;
#pragma unroll
        for (int r = 0; r < 16; ++r) acc1[r] = 0.f;
        const short8* w0 = WL + lane;
#pragma unroll
        for (int ch = 0; ch < 2; ++ch) {
            short8 a[10];
#pragma unroll
            for (int kt = 0; kt < 10; ++kt)
                a[kt] = *reinterpret_cast<const short8*>(arow + (ch * 10 + kt) * 16);
#pragma unroll
            for (int kt = 0; kt < 10; ++kt)
                acc1 = __builtin_amdgcn_mfma_f32_32x32x16_bf16(a[kt], w0[(ch * 10 + kt) * 64], acc1, 0, 0, 0);
        }
        const int col = lane & 31;
#pragma unroll
        for (int r = 0; r < 16; ++r) {
            const int row = wv * 32 + (r & 3) + 8 * (r >> 2) + 4 * (lane >> 5);
            if (row < NATOM) AL[row * 32 + col] = f2bf(acc1[r]);
        }
    }
    __syncthreads();

    // ---- re-stage WL = fc2 panel ----
    {
        const short8* w2 = pWfd + (size_t)ct * 20 * 64;
#pragma unroll
        for (int i = 0; i < 5; ++i) WL[i * 256 + tid] = w2[i * 256 + tid];
    }
    __syncthreads();

    // ---- GEMM_s: acc0 = af @ W_fc2[ct] (registers) ----
    f32x16 acc0;
#pragma unroll
    for (int r = 0; r < 16; ++r) acc0[r] = 0.f;
    {
        const short8* w0 = WL + lane;
#pragma unroll
        for (int ch = 0; ch < 2; ++ch) {
            short8 a[10];
#pragma unroll
            for (int kt = 0; kt < 10; ++kt)
                a[kt] = *reinterpret_cast<const short8*>(arow + (ch * 10 + kt) * 16);
#pragma unroll
            for (int kt = 0; kt < 10; ++kt)
                acc0 = __builtin_amdgcn_mfma_f32_32x32x16_bf16(a[kt], w0[(ch * 10 + kt) * 64], acc0, 0, 0, 0);
        }
    }
    __syncthreads();   // WL reads done before GL overwrite

    // ---- product: GL[row][c] = sum_j mask (A2f[ag]*bnb[bg]) ----
    for (int i = tid; i < NATOM * 16; i += 256) {
        const int row = i >> 4, cp = i & 15;
        float lo = 0.f, hi = 0.f;
#pragma unroll
        for (int j = 0; j < NNB; ++j) {
            const u16 w = PLh[row * NNB + j];
            if (w & 0x8000) {
                const int a  = (w >> 8) & 0x7f;
                const int bo = w & 0xff;
                const u32 va = *reinterpret_cast<const u32*>(&AL[a * 32 + 2 * cp]);
                const u32 vb = BL[bo * 16 + cp];
                lo += bflo(va) * bflo(vb);
                hi += bfhi(va) * bfhi(vb);
            }
        }
        GL[row * 32 + 2 * cp]     = lo;
        GL[row * 32 + 2 * cp + 1] = hi;
    }
    __syncthreads();

    // ---- epilogue ----
    {
        const int col = ct * 32 + (lane & 31);
        if (col < HREAL) {
#pragma unroll
            for (int r = 0; r < 16; ++r) {
                const int row = wv * 32 + (r & 3) + 8 * (r >> 2) + 4 * (lane >> 5);
                if (row < NATOM) {
                    float v = 0.f;
                    if (ML[row]) v = bfu(f2bf(acc0[r])) * GL[row * 32 + (lane & 31)];
                    out[(size_t)(b * NATOM + row) * HREAL + col] = v;
                }
            }
        }
    }
}

extern "C" void kernel_launch(void* const* d_in, const int* in_sizes, int n_in,
                              void* d_out, int out_size, void* d_ws, size_t ws_size,
                              hipStream_t stream) {
    const float* A1        = (const float*)d_in[0];
    const float* bond      = (const float*)d_in[1];
    const int*   ag        = (const int*)d_in[2];
    const int*   bg        = (const int*)d_in[3];
    const int*   maskn     = (const int*)d_in[6];
    const int*   maska     = (const int*)d_in[7];
    const float* W_fc1     = (const float*)d_in[8];
    const float* W_gc_nei  = (const float*)d_in[9];
    const float* b_gc_nei  = (const float*)d_in[10];
    const float* W_gc_atom = (const float*)d_in[11];
    const float* b_gc_atom = (const float*)d_in[12];
    const float* W_fc2a    = (const float*)d_in[13];
    const float* W_fc2b    = (const float*)d_in[14];
    const float* W_fc2     = (const float*)d_in[15];
    float* out = (float*)d_out;

    // ---- workspace carve-up ----
    char* p = (char*)d_ws;
    auto alloc = [&](size_t bytes) { char* r = p; p += (bytes + 63) & ~(size_t)63; return r; };
    __hip_bfloat16* af0    = (__hip_bfloat16*)alloc((size_t)MA * HP * 2);
    __hip_bfloat16* af1    = (__hip_bfloat16*)alloc((size_t)MA * HP * 2);
    __hip_bfloat16* neib   = (__hip_bfloat16*)alloc((size_t)MA * HP * 2);
    u16*            pk16   = (u16*)alloc((size_t)MA * NNB * 2);         // packed nbr table u16
    short8* pWnei= (short8*)alloc((size_t)NCT32 * 20 * 64 * 16);        // gc_nei[:H]   K=320
    short8* pWga = (short8*)alloc((size_t)NCT32 * 40 * 64 * 16);        // gc_atom cat  K=640
    short8* pWfd = (short8*)alloc((size_t)2 * NCT32 * 20 * 64 * 16);    // fc2 | fc2a   K=320, 20 ct

    // ---- front: fc1 (self-packed) + packs + pk16 in ONE launch ----
    Front fr;
    fr.A1 = A1; fr.W_fc1 = W_fc1; fr.af0 = af0;
    fr.mn = maskn; fr.agp = ag; fr.bgp = bg; fr.pk16 = pk16;
    //          W                                  dst                          Kreal  KT KTf off blk0
    fr.j[0] = { W_gc_nei,                          pWnei,                       HREAL, 20, 20, 0,  300 };
    fr.j[1] = { W_gc_atom,                         pWga,                        HREAL, 20, 40, 0,  350 };
    fr.j[2] = { W_gc_atom + (size_t)HREAL * HREAL, pWga,                        HREAL, 20, 40, 20, 400 };
    fr.j[3] = { W_fc2,                             pWfd,                        HREAL, 20, 20, 0,  450 };
    fr.j[4] = { W_fc2a,                            pWfd + (size_t)NCT32*20*64,  HREAL, 20, 20, 0,  500 };
    k_front<<<dim3(FRONT_BLKS), dim3(256), FRONT_LDS, stream>>>(fr);

    // ---- opt-in LDS > 64 KB (bot only) ----
    static int attr_done = 0;
    if (!attr_done) {
        hipFuncSetAttribute((const void*)k_gemm_bot, hipFuncAttributeMaxDynamicSharedMemorySize, BOT_LDS);
        attr_done = 1;
    }

    const dim3 gNUG(BATCH, NCT32);  // (64,10) -> 640 blocks @ 3/CU = 1 round
    const dim3 gBOT(MA / 128, 5);   // (60,5) 2-ct @ 2/CU = 1 round
    const dim3 t256(256);
    const float* Wgn_bond = W_gc_nei + (size_t)HREAL * HREAL;

    // ---- graph-conv iterations ----
    const __hip_bfloat16* af = af0;
    __hip_bfloat16* afn = af1;
    for (int it = 0; it < 2; ++it) {
        k_nu_gather<<<gNUG, t256, NUG_LDS, stream>>>(
            af, pWnei, bond, Wgn_bond, b_gc_nei, pk16, (u32*)neib);
        k_gemm_bot<<<gBOT, t256, BOT_LDS, stream>>>(af, neib, pWga, b_gc_atom, afn);
        const __hip_bfloat16* t = afn; afn = (__hip_bfloat16*)af; af = t;
    }

    // ---- fused final layer ----
    k_final_fused<<<gNUG, t256, FIN_LDS, stream>>>(
        af, pWfd, bond, W_fc2b, pk16, maska, out);
}

// Round 13
// 128.860 us; speedup vs baseline: 1.0062x; 1.0062x over previous
//
#include <hip/hip_runtime.h>
#include <hip/hip_bf16.h>

// Problem constants
#define BATCH 64
#define NATOM 120
#define NNB 10
#define NBOND 250
#define AFDIM 82
#define BFDIM 6
#define HREAL 300
#define HP 320            // padded H (bf16 activation row stride); pad cols hold exact 0
#define NCT32 10          // 10 col-tiles of 32 -> 320
#define MA (BATCH*NATOM)  // 7680
#define MB (BATCH*NBOND)  // 16000

typedef short short8 __attribute__((ext_vector_type(8)));   // 8 bf16 (4 VGPRs)
typedef float f32x16 __attribute__((ext_vector_type(16)));  // 32x32 MFMA accumulator
typedef unsigned int u32;
typedef u32 u32x2 __attribute__((ext_vector_type(2)));
typedef unsigned short u16;
typedef unsigned char u8;

__device__ __forceinline__ float bflo(u32 v) { return __builtin_bit_cast(float, v << 16); }
__device__ __forceinline__ float bfhi(u32 v) { return __builtin_bit_cast(float, v & 0xffff0000u); }
__device__ __forceinline__ float bfu(u16 v) { return __builtin_bit_cast(float, (u32)v << 16); }
__device__ __forceinline__ u16 f2bf(float f) {
    __hip_bfloat16 h = __float2bfloat16(f);
    return __builtin_bit_cast(u16, h);
}
__device__ __forceinline__ int imin(int a, int b) { return a < b ? a : b; }

// ---- async global->LDS 16B (direct DMA, no VGPR round-trip). Drained by the
// vmcnt(0) the compiler emits before the next __syncthreads(). Dest layout is
// wave-uniform base + lane*16 (m104 semantics) -- our Wl[i*256+tid] pattern
// satisfies this exactly. ----
__device__ __forceinline__ void gl_lds16(void* lds, const void* gsrc) {
    __builtin_amdgcn_global_load_lds(
        (const __attribute__((address_space(1))) u32*)gsrc,
        (__attribute__((address_space(3))) u32*)lds,
        16, 0, 0);
}

// ================= front dispatch: fc1 (self-packed W) + 5 weight packs + pk16, ONE launch =================
struct PackJob { const float* W; short8* dst; int Kreal, KT, KTfull, ktOff, blk0; };
struct Front {
    const float *A1, *W_fc1;
    __hip_bfloat16* af0;
    const int *mn, *agp, *bgp; u16* pk16;        // pk16[i] = mask<<15 | ag<<8 | bg
    PackJob j[5];
};

#define FC1_TILES  300    // (60 bx) x (5 by)
#define PACK_BASE2 300    // 5 jobs x 50 blocks
#define PK_BASE2   550
#define FRONT_BLKS 850
#define FRONT_LDS  (2 * 6 * 64 * 16)   // 12288 B (fc1 W panel)

__global__ __launch_bounds__(256) void k_front(Front cfg) {
    extern __shared__ short8 Wl[];
    const int bid = blockIdx.x;
    const int tid = threadIdx.x;
    if (bid < FC1_TILES) {
        // ---- fc1: af0 = relu(A1 @ W_fc1); W panel self-packed from fp32 ----
        const int bx   = bid % 60;
        const int ct0  = (bid / 60) * 2;
        const int lane = tid & 63;
        const int wv   = tid >> 6;
#pragma unroll
        for (int i = 0; i < 3; ++i) {            // 768 panel entries / 256 threads
            const int id = i * 256 + tid;
            const int l2 = id & 63;
            const int kt = (id >> 6) % 6;
            const int c  = id / (6 * 64);
            const int col = (ct0 + c) * 32 + (l2 & 31);
            const int kbase = kt * 16 + (l2 >> 5) * 8;
            short8 v;
#pragma unroll
            for (int jj = 0; jj < 8; ++jj) {
                const int k = kbase + jj;
                const float f = (k < AFDIM && col < HREAL) ? cfg.W_fc1[(size_t)k * HREAL + col] : 0.f;
                v[jj] = (short)f2bf(f);
            }
            Wl[(c * 6 + kt) * 64 + l2] = v;
        }
        __syncthreads();

        const int m0   = bx * 128 + wv * 32;
        const int r1   = m0 + (lane & 31);
        const int koff = (lane >> 5) * 8;
        const float* src = cfg.A1 + (size_t)r1 * AFDIM;
        short8 a[6];
#pragma unroll
        for (int g = 0; g < 6; ++g) {
#pragma unroll
            for (int jj = 0; jj < 8; ++jj) {
                const int k = g * 16 + koff + jj;
                const float f = (k < AFDIM) ? src[k] : 0.f;
                a[g][jj] = (short)f2bf(f);
            }
        }
        f32x16 acc[2];
#pragma unroll
        for (int r = 0; r < 16; ++r) { acc[0][r] = 0.f; acc[1][r] = 0.f; }
        const short8* w0 = Wl + lane;
        const short8* w1 = Wl + 6 * 64 + lane;
#pragma unroll
        for (int g = 0; g < 6; ++g) {
            acc[0] = __builtin_amdgcn_mfma_f32_32x32x16_bf16(a[g], w0[g * 64], acc[0], 0, 0, 0);
            acc[1] = __builtin_amdgcn_mfma_f32_32x32x16_bf16(a[g], w1[g * 64], acc[1], 0, 0, 0);
        }
#pragma unroll
        for (int c = 0; c < 2; ++c) {
            const int col = (ct0 + c) * 32 + (lane & 31);
#pragma unroll
            for (int r = 0; r < 16; ++r) {
                const int row = m0 + (r & 3) + 8 * (r >> 2) + 4 * (lane >> 5);
                cfg.af0[(size_t)row * HP + col] = __float2bfloat16(fmaxf(acc[c][r], 0.f));
            }
        }
    } else if (bid < PK_BASE2) {
        // ---- weight packs (consumed only by later dispatches) ----
        int ji = 0;
#pragma unroll
        for (int i = 1; i < 5; ++i) if (bid >= cfg.j[i].blk0) ji = i;
        const PackJob J = cfg.j[ji];
        int id = (bid - J.blk0) * 256 + tid;
        int n = NCT32 * J.KT * 64;
        if (id >= n) return;
        int lane = id & 63;
        int kt = (id >> 6) % J.KT;
        int ct = id / (J.KT * 64);
        int col = ct * 32 + (lane & 31);
        int kbase = kt * 16 + (lane >> 5) * 8;
        short8 v;
#pragma unroll
        for (int jj = 0; jj < 8; ++jj) {
            int k = kbase + jj;
            float f = (k < J.Kreal && col < HREAL) ? J.W[(size_t)k * HREAL + col] : 0.f;
            v[jj] = (short)f2bf(f);
        }
        J.dst[(size_t)(ct * J.KTfull + J.ktOff + kt) * 64 + lane] = v;
    } else {
        int id = (bid - PK_BASE2) * 256 + tid;    // exact multiple (76800)
        u16 w = 0;
        if (cfg.mn[id])
            w = (u16)(0x8000u | ((u32)cfg.agp[id] << 8) | (u32)cfg.bgp[id]);
        cfg.pk16[id] = w;
    }
}

// ================= bot GEMM: afn = relu([af|nei]@W_ga + b_ga), 2 ct, 80KB panel =================
// W panel staged via async global_load_lds (direct DMA), drained at the barrier.
#define BOT_LDS (2 * 40 * 64 * 16)     // 81920 B -> 2 blocks/CU, 300 blocks = 1 round
__global__ __launch_bounds__(256)
void k_gemm_bot(const __hip_bfloat16* __restrict__ af,
                const __hip_bfloat16* __restrict__ neib,
                const short8* __restrict__ W,
                const float* __restrict__ b_ga,
                __hip_bfloat16* __restrict__ afn) {
    extern __shared__ short8 Wl[];             // [2*40*64]
    const int tid  = threadIdx.x;
    const int lane = tid & 63;
    const int wv   = tid >> 6;
    const int m0   = blockIdx.x * 128 + wv * 32;
    const int ct0  = blockIdx.y * 2;
    const int r1   = m0 + (lane & 31);
    const int koff = (lane >> 5) * 8;

    {
        const short8* wsrc = W + (size_t)ct0 * 40 * 64;
#pragma unroll
        for (int i = 0; i < 20; ++i)
            gl_lds16(&Wl[i * 256 + tid], wsrc + i * 256 + tid);
    }
    __syncthreads();   // compiler drains vmcnt(0) here -> LDS panel valid

    f32x16 acc[2];
#pragma unroll
    for (int r = 0; r < 16; ++r) { acc[0][r] = 0.f; acc[1][r] = 0.f; }
    const short8* w0 = Wl + lane;
    const short8* w1 = Wl + 40 * 64 + lane;

#pragma unroll
    for (int ch = 0; ch < 4; ++ch) {
        short8 a[10];
#pragma unroll
        for (int kt = 0; kt < 10; ++kt) {
            const int g = ch * 10 + kt;
            if (g < 20)
                a[kt] = *reinterpret_cast<const short8*>(af + (size_t)r1 * HP + g * 16 + koff);
            else
                a[kt] = *reinterpret_cast<const short8*>(neib + (size_t)r1 * HP + (g - 20) * 16 + koff);
        }
#pragma unroll
        for (int kt = 0; kt < 10; ++kt) {
            const int g = ch * 10 + kt;
            acc[0] = __builtin_amdgcn_mfma_f32_32x32x16_bf16(a[kt], w0[g * 64], acc[0], 0, 0, 0);
            acc[1] = __builtin_amdgcn_mfma_f32_32x32x16_bf16(a[kt], w1[g * 64], acc[1], 0, 0, 0);
        }
    }

#pragma unroll
    for (int c = 0; c < 2; ++c) {
        const int col = (ct0 + c) * 32 + (lane & 31);
        const float bb = (col < HREAL) ? b_ga[col] : 0.f;
#pragma unroll
        for (int r = 0; r < 16; ++r) {
            const int row = m0 + (r & 3) + 8 * (r >> 2) + 4 * (lane >> 5);
            afn[(size_t)row * HP + col] = __float2bfloat16(fmaxf(acc[c][r] + bb, 0.f));
        }
    }
}

// ================= fused nu-GEMM + gather; 50,944 B LDS -> 3 blocks/CU, 1 round =================
#define NUG_LDS (20480 + 7680 + 16000 + 2400 + 4000 + 384)   // 50944
__global__ __launch_bounds__(256)
void k_nu_gather(const __hip_bfloat16* __restrict__ af,
                 const short8* __restrict__ pWnei,
                 const float* __restrict__ bond,      // [B][250][6] fp32
                 const float* __restrict__ Wgn_bond,  // W_gc_nei + 300*300, [6][300]
                 const float* __restrict__ b_gn,      // [300]
                 const u16* __restrict__ pk16,
                 u32* __restrict__ nei) {             // [MA][160]
    extern __shared__ char smraw[];
    short8* WL  = (short8*)smraw;                  // [20*64]
    u16*    TL  = (u16*)(smraw + 20480);           // [120][32]
    u32*    BL  = (u32*)(smraw + 28160);           // [250][16] bondgc slice
    u16*    PLh = (u16*)(smraw + 44160);           // [1200]
    u16*    BFL = (u16*)(smraw + 46560);           // [250][8] bond bf16
    u16*    WS  = (u16*)(smraw + 50560);           // [6][32]  W bond-part slice bf16
    const int b   = blockIdx.x;
    const int ct  = blockIdx.y;
    const int tid = threadIdx.x;

    // ---- stage (W panel via async DMA; scalar stages unchanged) ----
    {
        const short8* wsrc = pWnei + (size_t)ct * 20 * 64;
#pragma unroll
        for (int i = 0; i < 5; ++i)
            gl_lds16(&WL[i * 256 + tid], wsrc + i * 256 + tid);
    }
    for (int i = tid; i < NBOND * 8; i += 256) {
        const int r = i >> 3, k = i & 7;
        const float f = (k < BFDIM) ? bond[(size_t)(b * NBOND + r) * BFDIM + k] : 0.f;
        BFL[i] = f2bf(f);
    }
    if (tid < 192) {
        const int k = tid >> 5, c = tid & 31;
        const int col = ct * 32 + c;
        const float f = (col < HREAL) ? Wgn_bond[(size_t)k * HREAL + col] : 0.f;
        WS[tid] = f2bf(f);
    }
    for (int i = tid; i < 600; i += 256)
        reinterpret_cast<u32*>(PLh)[i] = reinterpret_cast<const u32*>(pk16)[(size_t)b * 600 + i];
    __syncthreads();

    // ---- bondgc slice: BL[r][cp] = bf16pair( sum_k bond[r,k]*W[k,col] + bias ) ----
    for (int i = tid; i < NBOND * 16; i += 256) {
        const int r = i >> 4, cp = i & 15;
        const int col0 = ct * 32 + 2 * cp;
        float lo = 0.f, hi = 0.f;
#pragma unroll
        for (int k = 0; k < BFDIM; ++k) {
            const float bv = bfu(BFL[r * 8 + k]);
            const u32 wv2 = *reinterpret_cast<const u32*>(&WS[k * 32 + 2 * cp]);
            lo += bv * bflo(wv2);
            hi += bv * bfhi(wv2);
        }
        const float v0 = (col0     < HREAL) ? lo + b_gn[col0]     : 0.f;
        const float v1 = (col0 + 1 < HREAL) ? hi + b_gn[col0 + 1] : 0.f;
        BL[r * 16 + cp] = (u32)f2bf(v0) | ((u32)f2bf(v1) << 16);
    }

    // ---- GEMM: TL = af[b] @ W_nei[ct] ----
    {
        const int lane = tid & 63;
        const int wv   = tid >> 6;
        const int r1   = imin(wv * 32 + (lane & 31), NATOM - 1);
        const int koff = (lane >> 5) * 8;
        const __hip_bfloat16* arow = af + (size_t)(b * NATOM + r1) * HP + koff;
        f32x16 acc;
#pragma unroll
        for (int r = 0; r < 16; ++r) acc[r] = 0.f;
        const short8* w0 = WL + lane;
#pragma unroll
        for (int ch = 0; ch < 2; ++ch) {
            short8 a[10];
#pragma unroll
            for (int kt = 0; kt < 10; ++kt)
                a[kt] = *reinterpret_cast<const short8*>(arow + (ch * 10 + kt) * 16);
#pragma unroll
            for (int kt = 0; kt < 10; ++kt)
                acc = __builtin_amdgcn_mfma_f32_32x32x16_bf16(a[kt], w0[(ch * 10 + kt) * 64], acc, 0, 0, 0);
        }
        const int col = lane & 31;
#pragma unroll
        for (int r = 0; r < 16; ++r) {
            const int row = wv * 32 + (r & 3) + 8 * (r >> 2) + 4 * (lane >> 5);
            if (row < NATOM) TL[row * 32 + col] = f2bf(acc[r]);
        }
    }
    __syncthreads();

    // ---- gather: nei = sum_j relu(T[ag] + bondgc[bg]) ----
    for (int i = tid; i < NATOM * 16; i += 256) {
        const int row = i >> 4, cp = i & 15;
        float lo = 0.f, hi = 0.f;
#pragma unroll
        for (int j = 0; j < NNB; ++j) {
            const u16 w = PLh[row * NNB + j];
            if (w & 0x8000) {
                const int a  = (w >> 8) & 0x7f;
                const int bo = w & 0xff;
                const u32 ta = *reinterpret_cast<const u32*>(&TL[a * 32 + 2 * cp]);
                const u32 tb = BL[bo * 16 + cp];
                lo += fmaxf(bflo(ta) + bflo(tb), 0.f);
                hi += fmaxf(bfhi(ta) + bfhi(tb), 0.f);
            }
        }
        nei[(size_t)(b * NATOM + row) * (HP / 2) + ct * 16 + cp] =
            (u32)f2bf(lo) | ((u32)f2bf(hi) << 16);
    }
}

// ================= fused final; 51,064 B -> 3 blocks/CU, 1 round =================
#define FIN_LDS (20480 + 7680 + 16000 + 2400 + 120 + 4000 + 384)   // 51064
__global__ __launch_bounds__(256)
void k_final_fused(const __hip_bfloat16* __restrict__ af,
                   const short8* __restrict__ pWfd,    // fc2 ct 0..9 | fc2a ct 10..19
                   const float* __restrict__ bond,     // [B][250][6] fp32
                   const float* __restrict__ W_fc2b,   // [6][300] fp32
                   const u16* __restrict__ pk16,
                   const int* __restrict__ maska,
                   float* __restrict__ out) {          // [MA][300]
    extern __shared__ char smraw[];
    short8* WL  = (short8*)smraw;                      // [20*64]
    u16*    AL  = (u16*)(smraw + 20480);               // A2f [120][32]
    u32*    BL  = (u32*)(smraw + 28160);               // bnb [250][16]
    u16*    PLh = (u16*)(smraw + 44160);               // [1200]
    u8*     ML  = (u8*)(smraw + 46560);                // [120]
    u16*    BFL = (u16*)(smraw + 46680);               // [250][8]
    u16*    WS  = (u16*)(smraw + 50680);               // [6][32]
    float*  GL  = (float*)smraw;                       // [120][32] gathered sums (reuses WL)
    const int b   = blockIdx.x;
    const int ct  = blockIdx.y;
    const int tid = threadIdx.x;
    const int lane = tid & 63;
    const int wv   = tid >> 6;

    // ---- stage A (fc2a panel via async DMA) ----
    {
        const short8* w2a = pWfd + (size_t)(NCT32 + ct) * 20 * 64;
#pragma unroll
        for (int i = 0; i < 5; ++i)
            gl_lds16(&WL[i * 256 + tid], w2a + i * 256 + tid);
    }
    for (int i = tid; i < NBOND * 8; i += 256) {
        const int r = i >> 3, k = i & 7;
        const float f = (k < BFDIM) ? bond[(size_t)(b * NBOND + r) * BFDIM + k] : 0.f;
        BFL[i] = f2bf(f);
    }
    if (tid < 192) {
        const int k = tid >> 5, c = tid & 31;
        const int col = ct * 32 + c;
        const float f = (col < HREAL) ? W_fc2b[(size_t)k * HREAL + col] : 0.f;
        WS[tid] = f2bf(f);
    }
    for (int i = tid; i < 600; i += 256)
        reinterpret_cast<u32*>(PLh)[i] = reinterpret_cast<const u32*>(pk16)[(size_t)b * 600 + i];
    for (int i = tid; i < NATOM; i += 256) ML[i] = (u8)(maska[b * NATOM + i] != 0);
    __syncthreads();

    // ---- bnb slice ----
    for (int i = tid; i < NBOND * 16; i += 256) {
        const int r = i >> 4, cp = i & 15;
        float lo = 0.f, hi = 0.f;
#pragma unroll
        for (int k = 0; k < BFDIM; ++k) {
            const float bv = bfu(BFL[r * 8 + k]);
            const u32 wv2 = *reinterpret_cast<const u32*>(&WS[k * 32 + 2 * cp]);
            lo += bv * bflo(wv2);
            hi += bv * bfhi(wv2);
        }
        BL[r * 16 + cp] = (u32)f2bf(lo) | ((u32)f2bf(hi) << 16);
    }

    // ---- GEMM_a: AL = af @ W_fc2a[ct] ----
    const int r1   = imin(wv * 32 + (lane & 31), NATOM - 1);
    const int koff = (lane >> 5) * 8;
    const __hip_bfloat16* arow = af + (size_t)(b * NATOM + r1) * HP + koff;
    {
        f32x16 acc1;
#pragma unroll
        for (int r = 0; r < 16; ++r) acc1[r] = 0.f;
        const short8* w0 = WL + lane;
#pragma unroll
        for (int ch = 0; ch < 2; ++ch) {
            short8 a[10];
#pragma unroll
            for (int kt = 0; kt < 10; ++kt)
                a[kt] = *reinterpret_cast<const short8*>(arow + (ch * 10 + kt) * 16);
#pragma unroll
            for (int kt = 0; kt < 10; ++kt)
                acc1 = __builtin_amdgcn_mfma_f32_32x32x16_bf16(a[kt], w0[(ch * 10 + kt) * 64], acc1, 0, 0, 0);
        }
        const int col = lane & 31;
#pragma unroll
        for (int r = 0; r < 16; ++r) {
            const int row = wv * 32 + (r & 3) + 8 * (r >> 2) + 4 * (lane >> 5);
            if (row < NATOM) AL[row * 32 + col] = f2bf(acc1[r]);
        }
    }
    __syncthreads();

    // ---- re-stage WL = fc2 panel (async DMA) ----
    {
        const short8* w2 = pWfd + (size_t)ct * 20 * 64;
#pragma unroll
        for (int i = 0; i < 5; ++i)
            gl_lds16(&WL[i * 256 + tid], w2 + i * 256 + tid);
    }
    __syncthreads();

    // ---- GEMM_s: acc0 = af @ W_fc2[ct] (registers) ----
    f32x16 acc0;
#pragma unroll
    for (int r = 0; r < 16; ++r) acc0[r] = 0.f;
    {
        const short8* w0 = WL + lane;
#pragma unroll
        for (int ch = 0; ch < 2; ++ch) {
            short8 a[10];
#pragma unroll
            for (int kt = 0; kt < 10; ++kt)
                a[kt] = *reinterpret_cast<const short8*>(arow + (ch * 10 + kt) * 16);
#pragma unroll
            for (int kt = 0; kt < 10; ++kt)
                acc0 = __builtin_amdgcn_mfma_f32_32x32x16_bf16(a[kt], w0[(ch * 10 + kt) * 64], acc0, 0, 0, 0);
        }
    }
    __syncthreads();   // WL reads done before GL overwrite

    // ---- product: GL[row][c] = sum_j mask (A2f[ag]*bnb[bg]) ----
    for (int i = tid; i < NATOM * 16; i += 256) {
        const int row = i >> 4, cp = i & 15;
        float lo = 0.f, hi = 0.f;
#pragma unroll
        for (int j = 0; j < NNB; ++j) {
            const u16 w = PLh[row * NNB + j];
            if (w & 0x8000) {
                const int a  = (w >> 8) & 0x7f;
                const int bo = w & 0xff;
                const u32 va = *reinterpret_cast<const u32*>(&AL[a * 32 + 2 * cp]);
                const u32 vb = BL[bo * 16 + cp];
                lo += bflo(va) * bflo(vb);
                hi += bfhi(va) * bfhi(vb);
            }
        }
        GL[row * 32 + 2 * cp]     = lo;
        GL[row * 32 + 2 * cp + 1] = hi;
    }
    __syncthreads();

    // ---- epilogue ----
    {
        const int col = ct * 32 + (lane & 31);
        if (col < HREAL) {
#pragma unroll
            for (int r = 0; r < 16; ++r) {
                const int row = wv * 32 + (r & 3) + 8 * (r >> 2) + 4 * (lane >> 5);
                if (row < NATOM) {
                    float v = 0.f;
                    if (ML[row]) v = bfu(f2bf(acc0[r])) * GL[row * 32 + (lane & 31)];
                    out[(size_t)(b * NATOM + row) * HREAL + col] = v;
                }
            }
        }
    }
}

extern "C" void kernel_launch(void* const* d_in, const int* in_sizes, int n_in,
                              void* d_out, int out_size, void* d_ws, size_t ws_size,
                              hipStream_t stream) {
    const float* A1        = (const float*)d_in[0];
    const float* bond      = (const float*)d_in[1];
    const int*   ag        = (const int*)d_in[2];
    const int*   bg        = (const int*)d_in[3];
    const int*   maskn     = (const int*)d_in[6];
    const int*   maska     = (const int*)d_in[7];
    const float* W_fc1     = (const float*)d_in[8];
    const float* W_gc_nei  = (const float*)d_in[9];
    const float* b_gc_nei  = (const float*)d_in[10];
    const float* W_gc_atom = (const float*)d_in[11];
    const float* b_gc_atom = (const float*)d_in[12];
    const float* W_fc2a    = (const float*)d_in[13];
    const float* W_fc2b    = (const float*)d_in[14];
    const float* W_fc2     = (const float*)d_in[15];
    float* out = (float*)d_out;

    // ---- workspace carve-up ----
    char* p = (char*)d_ws;
    auto alloc = [&](size_t bytes) { char* r = p; p += (bytes + 63) & ~(size_t)63; return r; };
    __hip_bfloat16* af0    = (__hip_bfloat16*)alloc((size_t)MA * HP * 2);
    __hip_bfloat16* af1    = (__hip_bfloat16*)alloc((size_t)MA * HP * 2);
    __hip_bfloat16* neib   = (__hip_bfloat16*)alloc((size_t)MA * HP * 2);
    u16*            pk16   = (u16*)alloc((size_t)MA * NNB * 2);         // packed nbr table u16
    short8* pWnei= (short8*)alloc((size_t)NCT32 * 20 * 64 * 16);        // gc_nei[:H]   K=320
    short8* pWga = (short8*)alloc((size_t)NCT32 * 40 * 64 * 16);        // gc_atom cat  K=640
    short8* pWfd = (short8*)alloc((size_t)2 * NCT32 * 20 * 64 * 16);    // fc2 | fc2a   K=320, 20 ct

    // ---- front: fc1 (self-packed) + packs + pk16 in ONE launch ----
    Front fr;
    fr.A1 = A1; fr.W_fc1 = W_fc1; fr.af0 = af0;
    fr.mn = maskn; fr.agp = ag; fr.bgp = bg; fr.pk16 = pk16;
    //          W                                  dst                          Kreal  KT KTf off blk0
    fr.j[0] = { W_gc_nei,                          pWnei,                       HREAL, 20, 20, 0,  300 };
    fr.j[1] = { W_gc_atom,                         pWga,                        HREAL, 20, 40, 0,  350 };
    fr.j[2] = { W_gc_atom + (size_t)HREAL * HREAL, pWga,                        HREAL, 20, 40, 20, 400 };
    fr.j[3] = { W_fc2,                             pWfd,                        HREAL, 20, 20, 0,  450 };
    fr.j[4] = { W_fc2a,                            pWfd + (size_t)NCT32*20*64,  HREAL, 20, 20, 0,  500 };
    k_front<<<dim3(FRONT_BLKS), dim3(256), FRONT_LDS, stream>>>(fr);

    // ---- opt-in LDS > 64 KB (bot only) ----
    static int attr_done = 0;
    if (!attr_done) {
        hipFuncSetAttribute((const void*)k_gemm_bot, hipFuncAttributeMaxDynamicSharedMemorySize, BOT_LDS);
        attr_done = 1;
    }

    const dim3 gNUG(BATCH, NCT32);  // (64,10) -> 640 blocks @ 3/CU = 1 round
    const dim3 gBOT(MA / 128, 5);   // (60,5) 2-ct @ 2/CU = 1 round
    const dim3 t256(256);
    const float* Wgn_bond = W_gc_nei + (size_t)HREAL * HREAL;

    // ---- graph-conv iterations ----
    const __hip_bfloat16* af = af0;
    __hip_bfloat16* afn = af1;
    for (int it = 0; it < 2; ++it) {
        k_nu_gather<<<gNUG, t256, NUG_LDS, stream>>>(
            af, pWnei, bond, Wgn_bond, b_gc_nei, pk16, (u32*)neib);
        k_gemm_bot<<<gBOT, t256, BOT_LDS, stream>>>(af, neib, pWga, b_gc_atom, afn);
        const __hip_bfloat16* t = afn; afn = (__hip_bfloat16*)af; af = t;
    }

    // ---- fused final layer ----
    k_final_fused<<<gNUG, t256, FIN_LDS, stream>>>(
        af, pWfd, bond, W_fc2b, pk16, maska, out);
}